// Round 8
// baseline (622.940 us; speedup 1.0000x reference)
//
#include <hip/hip_runtime.h>
#include <hip/hip_bf16.h>

#define D_MODEL 768
#define D_INNER 1536
#define N_STATE 16
#define DT_RANK 96
#define KCONV   4
#define Bv      2
#define Lv      1024
#define MROWS   (Bv*Lv)   // 2048
#define CH      128       // scan chunk length
#define G       (Lv/CH)   // 8 chunks
#define PADL    68        // padded LDS row stride

typedef __attribute__((ext_vector_type(8))) short bf16x8;
typedef __attribute__((ext_vector_type(4))) float f32x4;

__device__ __forceinline__ void gll16(const void* g, void* l) {
    __builtin_amdgcn_global_load_lds(
        (const __attribute__((address_space(1))) void*)g,
        (__attribute__((address_space(3))) void*)l, 16, 0, 0);
}

__device__ __forceinline__ unsigned short f2bf(float f) {
    unsigned u = __builtin_bit_cast(unsigned, f);
    u += 0x7fffu + ((u >> 16) & 1u);
    return (unsigned short)(u >> 16);
}

template<int CTRL>
__device__ __forceinline__ float dpp_ror_add(float v) {
    int vi = __builtin_bit_cast(int, v);
    int mv = __builtin_amdgcn_update_dpp(vi, vi, CTRL, 0xf, 0xf, true);
    return v + __builtin_bit_cast(float, mv);
}

// ---------------- LayerNorm -> bf16 ----------------
__global__ __launch_bounds__(256)
void ln_kernel(const float* __restrict__ u, const float* __restrict__ w,
               const float* __restrict__ bvec, unsigned short* __restrict__ o)
{
    int row = blockIdx.x;
    const float* x = u + (size_t)row * D_MODEL;
    int t = threadIdx.x;
    float v0 = x[t], v1 = x[t + 256], v2 = x[t + 512];
    float s  = v0 + v1 + v2;
    float s2 = v0*v0 + v1*v1 + v2*v2;
    for (int off = 32; off; off >>= 1) {
        s  += __shfl_down(s, off);
        s2 += __shfl_down(s2, off);
    }
    __shared__ float rs[4], rs2[4];
    __shared__ float mu_s, rstd_s;
    int wid = t >> 6, lane = t & 63;
    if (lane == 0) { rs[wid] = s; rs2[wid] = s2; }
    __syncthreads();
    if (t == 0) {
        float S  = rs[0] + rs[1] + rs[2] + rs[3];
        float S2 = rs2[0] + rs2[1] + rs2[2] + rs2[3];
        float mu = S / (float)D_MODEL;
        float var = S2 / (float)D_MODEL - mu * mu;
        mu_s = mu;
        rstd_s = rsqrtf(var + 1e-5f);
    }
    __syncthreads();
    float mu = mu_s, r = rstd_s;
    unsigned short* orow = o + (size_t)row * D_MODEL;
    orow[t]       = f2bf((v0 - mu) * r * w[t]       + bvec[t]);
    orow[t + 256] = f2bf((v1 - mu) * r * w[t + 256] + bvec[t + 256]);
    orow[t + 512] = f2bf((v2 - mu) * r * w[t + 512] + bvec[t + 512]);
}

// ---------------- fp32 -> bf16 bulk convert ----------------
__global__ __launch_bounds__(256)
void f2b(const float* __restrict__ in, unsigned short* __restrict__ o, int n4)
{
    int i = blockIdx.x * 256 + threadIdx.x;
    if (i < n4) {
        float4 v = ((const float4*)in)[i];
        ushort4 r;
        r.x = f2bf(v.x); r.y = f2bf(v.y); r.z = f2bf(v.z); r.w = f2bf(v.w);
        ((ushort4*)o)[i] = r;
    }
}

// ---------------- bf16 MFMA GEMM: C[M,N](f32) = A[M,K](bf16,lda) * W[N,K]^T(bf16) ----------------
// act: 0=none, 2=softplus(+bias)
__global__ __launch_bounds__(256)
void gemm_mfma(const unsigned short* __restrict__ A, int lda, int revA, int Lr,
               const unsigned short* __restrict__ W,
               const float* __restrict__ bias, int act,
               const float* __restrict__ res,
               float* __restrict__ C,
               int M, int N, int K)
{
    __shared__ unsigned short As[128 * 32];
    __shared__ unsigned short Bs[128 * 32];
    const int tid = threadIdx.x;
    const int m0 = blockIdx.y * 128, n0 = blockIdx.x * 128;
    const int lane = tid & 63;
    const int w  = tid >> 6;
    const int wr = w >> 1, wc = w & 1;
    const int lm = lane & 15, lk = lane >> 4;

    const int srow = tid >> 2;
    const int skq  = (tid & 3) * 8;
    int arow0 = m0 + srow, arow1 = m0 + srow + 64;
    if (revA) {
        arow0 = (arow0 / Lr) * Lr + (Lr - 1 - arow0 % Lr);
        arow1 = (arow1 / Lr) * Lr + (Lr - 1 - arow1 % Lr);
    }
    const unsigned short* a0 = A + (size_t)arow0 * lda + skq;
    const unsigned short* a1 = A + (size_t)arow1 * lda + skq;
    const unsigned short* w0 = W + (size_t)(n0 + srow) * K + skq;
    const unsigned short* w1 = W + (size_t)(n0 + srow + 64) * K + skq;

    f32x4 acc[4][4] = {};

    for (int k0 = 0; k0 < K; k0 += 32) {
        __syncthreads();
        gll16(a0 + k0, &As[tid * 8]);
        gll16(a1 + k0, &As[2048 + tid * 8]);
        gll16(w0 + k0, &Bs[tid * 8]);
        gll16(w1 + k0, &Bs[2048 + tid * 8]);
        __syncthreads();

        bf16x8 af[4], bfr[4];
        #pragma unroll
        for (int i = 0; i < 4; i++) {
            af[i]  = *(const bf16x8*)&As[(wr * 64 + i * 16 + lm) * 32 + lk * 8];
            bfr[i] = *(const bf16x8*)&Bs[(wc * 64 + i * 16 + lm) * 32 + lk * 8];
        }
        #pragma unroll
        for (int i = 0; i < 4; i++)
            #pragma unroll
            for (int j = 0; j < 4; j++)
                acc[i][j] = __builtin_amdgcn_mfma_f32_16x16x32_bf16(af[i], bfr[j], acc[i][j], 0, 0, 0);
    }

    #pragma unroll
    for (int i = 0; i < 4; i++) {
        #pragma unroll
        for (int j = 0; j < 4; j++) {
            int row = m0 + wr * 64 + i * 16 + lk * 4;
            int col = n0 + wc * 64 + j * 16 + lm;
            #pragma unroll
            for (int r = 0; r < 4; r++) {
                float v = acc[i][j][r];
                if (bias) v += bias[col];
                if (act == 2) v = (v > 20.f) ? v : log1pf(__expf(v));
                if (res)  v += res[(size_t)(row + r) * N + col];
                C[(size_t)(row + r) * N + col] = v;
            }
        }
    }
}

// ---------------- Causal depthwise conv (K=4) + SiLU; dual fp32+bf16 out ----------------
__global__ __launch_bounds__(256)
void conv_silu(const float* __restrict__ xz, const float* __restrict__ w,
               const float* __restrict__ bias, float* __restrict__ xo,
               unsigned short* __restrict__ xbf)
{
    int t  = blockIdx.x * 256 + threadIdx.x;
    int d  = t % D_INNER;
    int lc = (t / D_INNER) % (Lv / 8);
    int b  = t / (D_INNER * (Lv / 8));
    int l0 = lc * 8;
    const float* src = xz + (size_t)b * Lv * (2 * D_INNER) + d;
    float w0 = w[d*4], w1 = w[d*4+1], w2 = w[d*4+2], w3 = w[d*4+3];
    float bb = bias[d];
    float v[11];
    #pragma unroll
    for (int j = 0; j < 11; j++) {
        int l = l0 - 3 + j;
        v[j] = (l >= 0) ? src[(size_t)l * (2 * D_INNER)] : 0.f;
    }
    size_t base = ((size_t)b * Lv + l0) * D_INNER + d;
    #pragma unroll
    for (int j = 0; j < 8; j++) {
        float a = bb + w0*v[j] + w1*v[j+1] + w2*v[j+2] + w3*v[j+3];
        a = a / (1.f + __expf(-a));  // SiLU
        xo[base + (size_t)j * D_INNER] = a;
        xbf[base + (size_t)j * D_INNER] = f2bf(a);
    }
}

// ================= Chunked selective scan =================
// Pass 1: per-chunk local scan (h0=0). Writes y_loc = C.h_local + x*D,
//         overwrites dt with running cumsum S, writes h_end per chunk.
__global__ __launch_bounds__(128)
void scan1(const float* __restrict__ xF, float* __restrict__ dtF,
           const float* __restrict__ xdF, const float* __restrict__ AlF,
           const float* __restrict__ DFp,
           const float* __restrict__ xB, float* __restrict__ dtB,
           const float* __restrict__ xdB, const float* __restrict__ AlB,
           const float* __restrict__ DBp,
           float* __restrict__ y_loc, float* __restrict__ h_end)
{
    const int br = blockIdx.z;
    const int bb = blockIdx.y >> 3, g = blockIdx.y & 7;
    const int d0 = blockIdx.x * 8;

    const float* x    = br ? xB  : xF;
    float*       dtp  = br ? dtB : dtF;
    const float* xd   = br ? xdB : xdF;
    const float* Alog = br ? AlB : AlF;
    const float* Dp   = br ? DBp : DFp;

    __shared__ float xs [2][8][PADL];
    __shared__ float dls[2][8][PADL];
    __shared__ float Bss[2][16][PADL];
    __shared__ float Css[2][16][PADL];

    const int t = threadIdx.x;
    const int n = t & 15, dloc = t >> 4;

    const float* xg  = x   + ((size_t)bb * Lv + g * CH) * D_INNER + d0;
    float*       dtg = dtp + ((size_t)bb * Lv + g * CH) * D_INNER + d0;
    const float* bcg = xd  + ((size_t)bb * Lv + g * CH) * 128;

    const int sl = t >> 1, sdq = (t & 1) * 4;
    const int bl0 = t >> 2,         bq0 = (t & 3) * 4;
    const int bl1 = (t + 128) >> 2, bq1 = ((t + 128) & 3) * 4;

    f32x4 rx, rdt, rb0, rb1, rc0, rc1;

    #define LOADG1(c) do {                                                       \
        int l0_ = (c) * 64;                                                      \
        rx  = *(const f32x4*)(xg  + (size_t)(l0_ + sl) * D_INNER + sdq);         \
        rdt = *(const f32x4*)(dtg + (size_t)(l0_ + sl) * D_INNER + sdq);         \
        rb0 = *(const f32x4*)(bcg + (size_t)(l0_ + bl0) * 128 + DT_RANK           + bq0); \
        rb1 = *(const f32x4*)(bcg + (size_t)(l0_ + bl1) * 128 + DT_RANK           + bq1); \
        rc0 = *(const f32x4*)(bcg + (size_t)(l0_ + bl0) * 128 + DT_RANK + N_STATE + bq0); \
        rc1 = *(const f32x4*)(bcg + (size_t)(l0_ + bl1) * 128 + DT_RANK + N_STATE + bq1); \
    } while (0)

    #define WRITEL1(p) do {                                                      \
        _Pragma("unroll")                                                        \
        for (int j = 0; j < 4; j++) {                                            \
            xs [p][sdq+j][sl] = rx[j];                                           \
            dls[p][sdq+j][sl] = rdt[j];                                          \
            Bss[p][bq0+j][bl0] = rb0[j];                                         \
            Bss[p][bq1+j][bl1] = rb1[j];                                         \
            Css[p][bq0+j][bl0] = rc0[j];                                         \
            Css[p][bq1+j][bl1] = rc1[j];                                         \
        }                                                                        \
    } while (0)

    const float An = -__expf(Alog[(d0 + dloc) * N_STATE + n]);
    const float Dd = Dp[d0 + dloc];
    float h = 0.f, srun = 0.f;

    LOADG1(0);
    WRITEL1(0);
    __syncthreads();

    for (int c = 0; c < 2; ++c) {
        const int p = c;
        if (c == 0) LOADG1(1);

        float yq[4] = {}, Sq[4] = {};
        #pragma unroll
        for (int gg = 0; gg < 16; ++gg) {
            f32x4 xv  = *(const f32x4*)&xs [p][dloc][gg*4];
            f32x4 dtv = *(const f32x4*)&dls[p][dloc][gg*4];
            f32x4 bv  = *(const f32x4*)&Bss[p][n][gg*4];
            f32x4 cv  = *(const f32x4*)&Css[p][n][gg*4];
            #pragma unroll
            for (int j = 0; j < 4; ++j) {
                const int l = gg * 4 + j;
                float dtl = dtv[j];
                float ab = __expf(dtl * An);
                h = fmaf(ab, h, dtl * xv[j] * bv[j]);
                srun += dtl;
                float contrib = h * cv[j];
                contrib = dpp_ror_add<0x121>(contrib);
                contrib = dpp_ror_add<0x122>(contrib);
                contrib = dpp_ror_add<0x124>(contrib);
                contrib = dpp_ror_add<0x128>(contrib);
                float y = contrib + xv[j] * Dd;
                if ((l & 15) == n) { yq[l >> 4] = y; Sq[l >> 4] = srun; }
            }
        }
        if (c == 0) WRITEL1(1);

        #pragma unroll
        for (int q = 0; q < 4; ++q) {
            int lc2 = c * 64 + q * 16 + n;     // within chunk
            int gl  = g * CH + lc2;            // within sequence
            y_loc[((size_t)(br*Bv + bb) * Lv + gl) * D_INNER + d0 + dloc] = yq[q];
            dtg[(size_t)lc2 * D_INNER + dloc] = Sq[q];   // overwrite dt with S
        }
        __syncthreads();
    }
    h_end[(((size_t)(br*Bv + bb) * G + g) * D_INNER + d0 + dloc) * 16 + n] = h;
    #undef LOADG1
    #undef WRITEL1
}

// Pass 2: combine chunk carries. One thread per (br,b,d,n).
__global__ __launch_bounds__(256)
void scan2(const float* __restrict__ SF, const float* __restrict__ SB,
           const float* __restrict__ AlF, const float* __restrict__ AlB,
           const float* __restrict__ h_end, float* __restrict__ h0buf)
{
    int idx = blockIdx.x * 256 + threadIdx.x;   // 98304
    int n = idx & 15;
    int rest = idx >> 4;
    int d  = rest % D_INNER;
    int bbr = rest / D_INNER;      // 0..3
    int bb = bbr & 1, br = bbr >> 1;

    const float* S    = br ? SB  : SF;
    const float* Alog = br ? AlB : AlF;
    float An = -__expf(Alog[d * N_STATE + n]);

    float h0 = 0.f;
    #pragma unroll
    for (int g = 0; g < G; ++g) {
        size_t base = (((size_t)(br*Bv + bb) * G + g) * D_INNER + d) * 16 + n;
        h0buf[base] = h0;
        float Send = S[((size_t)bb * Lv + g * CH + CH - 1) * D_INNER + d];
        h0 = __expf(An * Send) * h0 + h_end[base];
    }
}

// Pass 3: correction + gate + reversal, fully parallel over l.
__global__ __launch_bounds__(128)
void scan3(const float* __restrict__ SF, const float* __restrict__ xdF,
           const float* __restrict__ xzF, const float* __restrict__ AlF,
           const float* __restrict__ SB, const float* __restrict__ xdB,
           const float* __restrict__ xzB, const float* __restrict__ AlB,
           const float* __restrict__ y_loc, const float* __restrict__ h0buf,
           unsigned short* __restrict__ ycat)
{
    const int br = blockIdx.z;
    const int bb = blockIdx.y >> 3, g = blockIdx.y & 7;
    const int d0 = blockIdx.x * 8;

    const float* S    = br ? SB  : SF;
    const float* xd   = br ? xdB : xdF;
    const float* xz   = br ? xzB : xzF;
    const float* Alog = br ? AlB : AlF;

    __shared__ float Ss [2][8][PADL];
    __shared__ float zs [2][8][PADL];
    __shared__ float ys [2][8][PADL];
    __shared__ float Css[2][16][PADL];

    const int t = threadIdx.x;
    const int n = t & 15, dloc = t >> 4;

    const float* Sg  = S  + ((size_t)bb * Lv + g * CH) * D_INNER + d0;
    const float* zg  = xz + ((size_t)bb * Lv + g * CH) * (2*D_INNER) + D_INNER + d0;
    const float* yg  = y_loc + ((size_t)(br*Bv + bb) * Lv + g * CH) * D_INNER + d0;
    const float* bcg = xd + ((size_t)bb * Lv + g * CH) * 128;

    const int sl = t >> 1, sdq = (t & 1) * 4;
    const int bl0 = t >> 2,         bq0 = (t & 3) * 4;
    const int bl1 = (t + 128) >> 2, bq1 = ((t + 128) & 3) * 4;

    f32x4 rS, rz, ry, rc0, rc1;

    #define LOADG3(c) do {                                                       \
        int l0_ = (c) * 64;                                                      \
        rS = *(const f32x4*)(Sg + (size_t)(l0_ + sl) * D_INNER + sdq);           \
        rz = *(const f32x4*)(zg + (size_t)(l0_ + sl) * (2*D_INNER) + sdq);       \
        ry = *(const f32x4*)(yg + (size_t)(l0_ + sl) * D_INNER + sdq);           \
        rc0 = *(const f32x4*)(bcg + (size_t)(l0_ + bl0) * 128 + DT_RANK + N_STATE + bq0); \
        rc1 = *(const f32x4*)(bcg + (size_t)(l0_ + bl1) * 128 + DT_RANK + N_STATE + bq1); \
    } while (0)

    #define WRITEL3(p) do {                                                      \
        _Pragma("unroll")                                                        \
        for (int j = 0; j < 4; j++) {                                            \
            Ss[p][sdq+j][sl] = rS[j];                                            \
            zs[p][sdq+j][sl] = rz[j];                                            \
            ys[p][sdq+j][sl] = ry[j];                                            \
            Css[p][bq0+j][bl0] = rc0[j];                                         \
            Css[p][bq1+j][bl1] = rc1[j];                                         \
        }                                                                        \
    } while (0)

    const float An = -__expf(Alog[(d0 + dloc) * N_STATE + n]);
    const float h0 = h0buf[(((size_t)(br*Bv + bb) * G + g) * D_INNER + d0 + dloc) * 16 + n];

    LOADG3(0);
    WRITEL3(0);
    __syncthreads();

    for (int c = 0; c < 2; ++c) {
        const int p = c;
        if (c == 0) LOADG3(1);

        float yq[4] = {};
        #pragma unroll
        for (int gg = 0; gg < 16; ++gg) {
            f32x4 Sv = *(const f32x4*)&Ss [p][dloc][gg*4];
            f32x4 zv = *(const f32x4*)&zs [p][dloc][gg*4];
            f32x4 yv = *(const f32x4*)&ys [p][dloc][gg*4];
            f32x4 cv = *(const f32x4*)&Css[p][n][gg*4];
            #pragma unroll
            for (int j = 0; j < 4; ++j) {
                const int l = gg * 4 + j;
                float corr = cv[j] * __expf(An * Sv[j]) * h0;
                corr = dpp_ror_add<0x121>(corr);
                corr = dpp_ror_add<0x122>(corr);
                corr = dpp_ror_add<0x124>(corr);
                corr = dpp_ror_add<0x128>(corr);
                float y = yv[j] + corr;
                y *= zv[j] * __builtin_amdgcn_rcpf(1.f + __expf(-zv[j]));
                if ((l & 15) == n) yq[l >> 4] = y;
            }
        }
        if (c == 0) WRITEL3(1);

        #pragma unroll
        for (int q = 0; q < 4; ++q) {
            int gl = g * CH + c * 64 + q * 16 + n;
            int lo = br ? (Lv - 1 - gl) : gl;
            ycat[((size_t)bb * Lv + lo) * (2*D_INNER) + br * D_INNER + d0 + dloc] = f2bf(yq[q]);
        }
        __syncthreads();
    }
    #undef LOADG3
    #undef WRITEL3
}

extern "C" void kernel_launch(void* const* d_in, const int* in_sizes, int n_in,
                              void* d_out, int out_size, void* d_ws, size_t ws_size,
                              hipStream_t stream)
{
    (void)in_sizes; (void)n_in; (void)out_size; (void)ws_size;
    const float* u        = (const float*)d_in[0];
    const float* norm_w   = (const float*)d_in[1];
    const float* norm_b   = (const float*)d_in[2];
    const float* f_in_w   = (const float*)d_in[3];
    const float* f_conv_w = (const float*)d_in[4];
    const float* f_conv_b = (const float*)d_in[5];
    const float* f_Alog   = (const float*)d_in[6];
    const float* f_xproj  = (const float*)d_in[7];
    const float* f_dt_w   = (const float*)d_in[8];
    const float* f_dt_b   = (const float*)d_in[9];
    const float* f_D      = (const float*)d_in[10];
    const float* b_in_w   = (const float*)d_in[11];
    const float* b_conv_w = (const float*)d_in[12];
    const float* b_conv_b = (const float*)d_in[13];
    const float* b_Alog   = (const float*)d_in[14];
    const float* b_xproj  = (const float*)d_in[15];
    const float* b_dt_w   = (const float*)d_in[16];
    const float* b_dt_b   = (const float*)d_in[17];
    const float* b_D      = (const float*)d_in[18];
    const float* out_w    = (const float*)d_in[19];
    float* out = (float*)d_out;

    float* p = (float*)d_ws;
    unsigned short* un_bf = (unsigned short*)p;  p += (size_t)MROWS * D_MODEL;
    float* xz_f   = p;  p += (size_t)MROWS * 2 * D_INNER;
    float* xz_b   = p;  p += (size_t)MROWS * 2 * D_INNER;
    float* x_f    = p;  p += (size_t)MROWS * D_INNER;
    float* x_b    = p;  p += (size_t)MROWS * D_INNER;
    unsigned short* xbf_f = (unsigned short*)p;  p += (size_t)MROWS * D_INNER / 2;
    unsigned short* xbf_b = (unsigned short*)p;  p += (size_t)MROWS * D_INNER / 2;
    float* xdbl_f = p;  p += (size_t)MROWS * 128;
    float* xdbl_b = p;  p += (size_t)MROWS * 128;
    float* dt_f   = p;  p += (size_t)MROWS * D_INNER;       // becomes S after scan1
    float* dt_b_  = p;  p += (size_t)MROWS * D_INNER;       // becomes S after scan1
    unsigned short* yc_bf = (unsigned short*)p;  p += (size_t)MROWS * D_INNER;
    unsigned short* fw_bf = (unsigned short*)p;  p += (size_t)D_INNER * D_MODEL;
    unsigned short* bw_bf = (unsigned short*)p;  p += (size_t)D_INNER * D_MODEL;
    unsigned short* xwf_bf = (unsigned short*)p; p += (size_t)64 * D_INNER;
    unsigned short* xwb_bf = (unsigned short*)p; p += (size_t)64 * D_INNER;
    unsigned short* ow_bf = (unsigned short*)p;  p += (size_t)D_MODEL * D_INNER;
    float* y_loc  = p;  p += (size_t)2 * MROWS * D_INNER;                 // 25 MB
    float* h_end  = p;  p += (size_t)2 * Bv * G * D_INNER * N_STATE;      // 3.1 MB
    float* h0buf  = p;  p += (size_t)2 * Bv * G * D_INNER * N_STATE;      // 3.1 MB
    unsigned short* xdbf_f = (unsigned short*)p; p += (size_t)MROWS * 128 / 2;
    unsigned short* xdbf_b = (unsigned short*)p; p += (size_t)MROWS * 128 / 2;
    unsigned short* dtwf_bf = (unsigned short*)p; p += (size_t)D_INNER * DT_RANK / 2;
    unsigned short* dtwb_bf = (unsigned short*)p; p += (size_t)D_INNER * DT_RANK / 2;

    // 1. LayerNorm -> bf16
    ln_kernel<<<MROWS, 256, 0, stream>>>(u, norm_w, norm_b, un_bf);

    // 2. weight conversions to bf16
    f2b<<<(2*D_INNER*D_MODEL/4 + 255)/256, 256, 0, stream>>>(f_in_w, fw_bf, 2*D_INNER*D_MODEL/4);
    f2b<<<(2*D_INNER*D_MODEL/4 + 255)/256, 256, 0, stream>>>(b_in_w, bw_bf, 2*D_INNER*D_MODEL/4);
    f2b<<<(128*D_INNER/4 + 255)/256, 256, 0, stream>>>(f_xproj, xwf_bf, 128*D_INNER/4);
    f2b<<<(128*D_INNER/4 + 255)/256, 256, 0, stream>>>(b_xproj, xwb_bf, 128*D_INNER/4);
    f2b<<<(D_MODEL*2*D_INNER/4 + 255)/256, 256, 0, stream>>>(out_w, ow_bf, D_MODEL*2*D_INNER/4);
    f2b<<<(D_INNER*DT_RANK/4 + 255)/256, 256, 0, stream>>>(f_dt_w, dtwf_bf, D_INNER*DT_RANK/4);
    f2b<<<(D_INNER*DT_RANK/4 + 255)/256, 256, 0, stream>>>(b_dt_w, dtwb_bf, D_INNER*DT_RANK/4);

    // 3. in-proj GEMMs (bf16 MFMA; bwd reads reversed rows)
    gemm_mfma<<<dim3(2*D_INNER/128, MROWS/128), 256, 0, stream>>>(
        un_bf, D_MODEL, 0, Lv, fw_bf, nullptr, 0, nullptr, xz_f, MROWS, 2*D_INNER, D_MODEL);
    gemm_mfma<<<dim3(2*D_INNER/128, MROWS/128), 256, 0, stream>>>(
        un_bf, D_MODEL, 1, Lv, bw_bf, nullptr, 0, nullptr, xz_b, MROWS, 2*D_INNER, D_MODEL);

    // 4. conv + SiLU (dual fp32 + bf16 outputs)
    int convBlocks = (Bv * (Lv/8) * D_INNER) / 256;
    conv_silu<<<convBlocks, 256, 0, stream>>>(xz_f, f_conv_w, f_conv_b, x_f, xbf_f);
    conv_silu<<<convBlocks, 256, 0, stream>>>(xz_b, b_conv_w, b_conv_b, x_b, xbf_b);

    // 5. x-proj GEMMs (bf16 MFMA, N=128)
    gemm_mfma<<<dim3(1, MROWS/128), 256, 0, stream>>>(
        xbf_f, D_INNER, 0, Lv, xwf_bf, nullptr, 0, nullptr, xdbl_f, MROWS, 128, D_INNER);
    gemm_mfma<<<dim3(1, MROWS/128), 256, 0, stream>>>(
        xbf_b, D_INNER, 0, Lv, xwb_bf, nullptr, 0, nullptr, xdbl_b, MROWS, 128, D_INNER);

    // 6. xdbl -> bf16, then dt GEMMs (bf16 MFMA + bias + softplus)
    f2b<<<(MROWS*128/4 + 255)/256, 256, 0, stream>>>(xdbl_f, xdbf_f, MROWS*128/4);
    f2b<<<(MROWS*128/4 + 255)/256, 256, 0, stream>>>(xdbl_b, xdbf_b, MROWS*128/4);
    gemm_mfma<<<dim3(D_INNER/128, MROWS/128), 256, 0, stream>>>(
        xdbf_f, 128, 0, Lv, dtwf_bf, f_dt_b, 2, nullptr, dt_f, MROWS, D_INNER, DT_RANK);
    gemm_mfma<<<dim3(D_INNER/128, MROWS/128), 256, 0, stream>>>(
        xdbf_b, 128, 0, Lv, dtwb_bf, b_dt_b, 2, nullptr, dt_b_, MROWS, D_INNER, DT_RANK);

    // 7. chunked selective scan
    scan1<<<dim3(D_INNER/8, Bv*G, 2), 128, 0, stream>>>(
        x_f, dt_f, xdbl_f, f_Alog, f_D,
        x_b, dt_b_, xdbl_b, b_Alog, b_D, y_loc, h_end);
    scan2<<<(2*Bv*D_INNER*N_STATE)/256, 256, 0, stream>>>(
        dt_f, dt_b_, f_Alog, b_Alog, h_end, h0buf);
    scan3<<<dim3(D_INNER/8, Bv*G, 2), 128, 0, stream>>>(
        dt_f, xdbl_f, xz_f, f_Alog,
        dt_b_, xdbl_b, xz_b, b_Alog, y_loc, h0buf, yc_bf);

    // 8. out-proj GEMM (bf16 MFMA) + residual
    gemm_mfma<<<dim3(D_MODEL/128, MROWS/128), 256, 0, stream>>>(
        yc_bf, 2*D_INNER, 0, Lv, ow_bf, nullptr, 0, u, out, MROWS, D_MODEL, 2*D_INNER);
}

// Round 9
// 570.811 us; speedup vs baseline: 1.0913x; 1.0913x over previous
//
#include <hip/hip_runtime.h>
#include <hip/hip_bf16.h>

#define D_MODEL 768
#define D_INNER 1536
#define N_STATE 16
#define DT_RANK 96
#define KCONV   4
#define Bv      2
#define Lv      1024
#define MROWS   (Bv*Lv)   // 2048
#define CH      128       // scan chunk length
#define G       (Lv/CH)   // 8 chunks
#define PADL    68        // padded LDS row stride

typedef __attribute__((ext_vector_type(8))) short bf16x8;
typedef __attribute__((ext_vector_type(4))) float f32x4;

__device__ __forceinline__ void gll16(const void* g, void* l) {
    __builtin_amdgcn_global_load_lds(
        (const __attribute__((address_space(1))) void*)g,
        (__attribute__((address_space(3))) void*)l, 16, 0, 0);
}

__device__ __forceinline__ unsigned short f2bf(float f) {
    unsigned u = __builtin_bit_cast(unsigned, f);
    u += 0x7fffu + ((u >> 16) & 1u);
    return (unsigned short)(u >> 16);
}

template<int CTRL>
__device__ __forceinline__ float dpp_ror_add(float v) {
    int vi = __builtin_bit_cast(int, v);
    int mv = __builtin_amdgcn_update_dpp(vi, vi, CTRL, 0xf, 0xf, true);
    return v + __builtin_bit_cast(float, mv);
}

// ---------------- LayerNorm -> bf16 ----------------
__global__ __launch_bounds__(256)
void ln_kernel(const float* __restrict__ u, const float* __restrict__ w,
               const float* __restrict__ bvec, unsigned short* __restrict__ o)
{
    int row = blockIdx.x;
    const float* x = u + (size_t)row * D_MODEL;
    int t = threadIdx.x;
    float v0 = x[t], v1 = x[t + 256], v2 = x[t + 512];
    float s  = v0 + v1 + v2;
    float s2 = v0*v0 + v1*v1 + v2*v2;
    for (int off = 32; off; off >>= 1) {
        s  += __shfl_down(s, off);
        s2 += __shfl_down(s2, off);
    }
    __shared__ float rs[4], rs2[4];
    __shared__ float mu_s, rstd_s;
    int wid = t >> 6, lane = t & 63;
    if (lane == 0) { rs[wid] = s; rs2[wid] = s2; }
    __syncthreads();
    if (t == 0) {
        float S  = rs[0] + rs[1] + rs[2] + rs[3];
        float S2 = rs2[0] + rs2[1] + rs2[2] + rs2[3];
        float mu = S / (float)D_MODEL;
        float var = S2 / (float)D_MODEL - mu * mu;
        mu_s = mu;
        rstd_s = rsqrtf(var + 1e-5f);
    }
    __syncthreads();
    float mu = mu_s, r = rstd_s;
    unsigned short* orow = o + (size_t)row * D_MODEL;
    orow[t]       = f2bf((v0 - mu) * r * w[t]       + bvec[t]);
    orow[t + 256] = f2bf((v1 - mu) * r * w[t + 256] + bvec[t + 256]);
    orow[t + 512] = f2bf((v2 - mu) * r * w[t + 512] + bvec[t + 512]);
}

// ---------------- fp32 -> bf16 bulk convert ----------------
__global__ __launch_bounds__(256)
void f2b(const float* __restrict__ in, unsigned short* __restrict__ o, int n4)
{
    int i = blockIdx.x * 256 + threadIdx.x;
    if (i < n4) {
        float4 v = ((const float4*)in)[i];
        ushort4 r;
        r.x = f2bf(v.x); r.y = f2bf(v.y); r.z = f2bf(v.z); r.w = f2bf(v.w);
        ((ushort4*)o)[i] = r;
    }
}

// ---------------- bf16 MFMA GEMM: C[M,N](f32) = A[M,K](bf16,lda) * W[N,K]^T(bf16) ----------------
// act: 0=none, 2=softplus(+bias)
__global__ __launch_bounds__(256)
void gemm_mfma(const unsigned short* __restrict__ A, int lda, int revA, int Lr,
               const unsigned short* __restrict__ W,
               const float* __restrict__ bias, int act,
               const float* __restrict__ res,
               float* __restrict__ C,
               int M, int N, int K)
{
    __shared__ unsigned short As[128 * 32];
    __shared__ unsigned short Bs[128 * 32];
    const int tid = threadIdx.x;
    const int m0 = blockIdx.y * 128, n0 = blockIdx.x * 128;
    const int lane = tid & 63;
    const int w  = tid >> 6;
    const int wr = w >> 1, wc = w & 1;
    const int lm = lane & 15, lk = lane >> 4;

    const int srow = tid >> 2;
    const int skq  = (tid & 3) * 8;
    int arow0 = m0 + srow, arow1 = m0 + srow + 64;
    if (revA) {
        arow0 = (arow0 / Lr) * Lr + (Lr - 1 - arow0 % Lr);
        arow1 = (arow1 / Lr) * Lr + (Lr - 1 - arow1 % Lr);
    }
    const unsigned short* a0 = A + (size_t)arow0 * lda + skq;
    const unsigned short* a1 = A + (size_t)arow1 * lda + skq;
    const unsigned short* w0 = W + (size_t)(n0 + srow) * K + skq;
    const unsigned short* w1 = W + (size_t)(n0 + srow + 64) * K + skq;

    f32x4 acc[4][4] = {};

    for (int k0 = 0; k0 < K; k0 += 32) {
        __syncthreads();
        gll16(a0 + k0, &As[tid * 8]);
        gll16(a1 + k0, &As[2048 + tid * 8]);
        gll16(w0 + k0, &Bs[tid * 8]);
        gll16(w1 + k0, &Bs[2048 + tid * 8]);
        __syncthreads();

        bf16x8 af[4], bfr[4];
        #pragma unroll
        for (int i = 0; i < 4; i++) {
            af[i]  = *(const bf16x8*)&As[(wr * 64 + i * 16 + lm) * 32 + lk * 8];
            bfr[i] = *(const bf16x8*)&Bs[(wc * 64 + i * 16 + lm) * 32 + lk * 8];
        }
        #pragma unroll
        for (int i = 0; i < 4; i++)
            #pragma unroll
            for (int j = 0; j < 4; j++)
                acc[i][j] = __builtin_amdgcn_mfma_f32_16x16x32_bf16(af[i], bfr[j], acc[i][j], 0, 0, 0);
    }

    #pragma unroll
    for (int i = 0; i < 4; i++) {
        #pragma unroll
        for (int j = 0; j < 4; j++) {
            int row = m0 + wr * 64 + i * 16 + lk * 4;
            int col = n0 + wc * 64 + j * 16 + lm;
            #pragma unroll
            for (int r = 0; r < 4; r++) {
                float v = acc[i][j][r];
                if (bias) v += bias[col];
                if (act == 2) v = (v > 20.f) ? v : log1pf(__expf(v));
                if (res)  v += res[(size_t)(row + r) * N + col];
                C[(size_t)(row + r) * N + col] = v;
            }
        }
    }
}

// ---------------- Causal depthwise conv (K=4) + SiLU; dual fp32+bf16 out ----------------
__global__ __launch_bounds__(256)
void conv_silu(const float* __restrict__ xz, const float* __restrict__ w,
               const float* __restrict__ bias, float* __restrict__ xo,
               unsigned short* __restrict__ xbf)
{
    int t  = blockIdx.x * 256 + threadIdx.x;
    int d  = t % D_INNER;
    int lc = (t / D_INNER) % (Lv / 8);
    int b  = t / (D_INNER * (Lv / 8));
    int l0 = lc * 8;
    const float* src = xz + (size_t)b * Lv * (2 * D_INNER) + d;
    float w0 = w[d*4], w1 = w[d*4+1], w2 = w[d*4+2], w3 = w[d*4+3];
    float bb = bias[d];
    float v[11];
    #pragma unroll
    for (int j = 0; j < 11; j++) {
        int l = l0 - 3 + j;
        v[j] = (l >= 0) ? src[(size_t)l * (2 * D_INNER)] : 0.f;
    }
    size_t base = ((size_t)b * Lv + l0) * D_INNER + d;
    #pragma unroll
    for (int j = 0; j < 8; j++) {
        float a = bb + w0*v[j] + w1*v[j+1] + w2*v[j+2] + w3*v[j+3];
        a = a / (1.f + __expf(-a));  // SiLU
        xo[base + (size_t)j * D_INNER] = a;
        xbf[base + (size_t)j * D_INNER] = f2bf(a);
    }
}

// ================= Chunked selective scan (recompute structure) =================
// Pass 1 (light): per-chunk scan from h0=0 computing ONLY h_end and Send=sum(dt).
__global__ __launch_bounds__(128, 6)
void scan1(const float* __restrict__ xF, const float* __restrict__ dtF,
           const float* __restrict__ xdF, const float* __restrict__ AlF,
           const float* __restrict__ xB, const float* __restrict__ dtB,
           const float* __restrict__ xdB, const float* __restrict__ AlB,
           float* __restrict__ h_end, float* __restrict__ Send)
{
    const int br = blockIdx.z;
    const int bb = blockIdx.y >> 3, g = blockIdx.y & 7;
    const int d0 = blockIdx.x * 8;

    const float* x    = br ? xB  : xF;
    const float* dt   = br ? dtB : dtF;
    const float* xd   = br ? xdB : xdF;
    const float* Alog = br ? AlB : AlF;

    __shared__ float xs [2][8][PADL];
    __shared__ float dls[2][8][PADL];
    __shared__ float Bss[2][16][PADL];

    const int t = threadIdx.x;
    const int n = t & 15, dloc = t >> 4;

    const float* xg  = x  + ((size_t)bb * Lv + g * CH) * D_INNER + d0;
    const float* dtg = dt + ((size_t)bb * Lv + g * CH) * D_INNER + d0;
    const float* bcg = xd + ((size_t)bb * Lv + g * CH) * 128;

    const int sl = t >> 1, sdq = (t & 1) * 4;
    const int bl0 = t >> 2,         bq0 = (t & 3) * 4;
    const int bl1 = (t + 128) >> 2, bq1 = ((t + 128) & 3) * 4;

    f32x4 rx, rdt, rb0, rb1;

    #define LOADG1(c) do {                                                       \
        int l0_ = (c) * 64;                                                      \
        rx  = *(const f32x4*)(xg  + (size_t)(l0_ + sl) * D_INNER + sdq);         \
        rdt = *(const f32x4*)(dtg + (size_t)(l0_ + sl) * D_INNER + sdq);         \
        rb0 = *(const f32x4*)(bcg + (size_t)(l0_ + bl0) * 128 + DT_RANK + bq0);  \
        rb1 = *(const f32x4*)(bcg + (size_t)(l0_ + bl1) * 128 + DT_RANK + bq1);  \
    } while (0)

    #define WRITEL1(p) do {                                                     \
        _Pragma("unroll")                                                       \
        for (int j = 0; j < 4; j++) {                                           \
            xs [p][sdq+j][sl] = rx[j];                                          \
            dls[p][sdq+j][sl] = rdt[j];                                         \
            Bss[p][bq0+j][bl0] = rb0[j];                                        \
            Bss[p][bq1+j][bl1] = rb1[j];                                        \
        }                                                                       \
    } while (0)

    const float An = -__expf(Alog[(d0 + dloc) * N_STATE + n]);
    float h = 0.f, srun = 0.f;

    LOADG1(0);
    WRITEL1(0);
    __syncthreads();

    for (int c = 0; c < 2; ++c) {
        const int p = c;
        if (c == 0) LOADG1(1);

        #pragma unroll
        for (int gg = 0; gg < 16; ++gg) {
            f32x4 xv  = *(const f32x4*)&xs [p][dloc][gg*4];
            f32x4 dtv = *(const f32x4*)&dls[p][dloc][gg*4];
            f32x4 bv  = *(const f32x4*)&Bss[p][n][gg*4];
            #pragma unroll
            for (int j = 0; j < 4; ++j) {
                float ab = __expf(dtv[j] * An);
                h = fmaf(ab, h, dtv[j] * xv[j] * bv[j]);
                srun += dtv[j];
            }
        }
        if (c == 0) { WRITEL1(1); }
        __syncthreads();
    }
    h_end[(((size_t)(br*Bv + bb) * G + g) * D_INNER + d0 + dloc) * 16 + n] = h;
    if (n == 0)
        Send[((size_t)(br*Bv + bb) * G + g) * D_INNER + d0 + dloc] = srun;
    #undef LOADG1
    #undef WRITEL1
}

// Pass 2: combine chunk carries. One thread per (br,b,d,n).
__global__ __launch_bounds__(256)
void scan2(const float* __restrict__ Send,
           const float* __restrict__ AlF, const float* __restrict__ AlB,
           const float* __restrict__ h_end, float* __restrict__ h0buf)
{
    int idx = blockIdx.x * 256 + threadIdx.x;   // 98304
    int n = idx & 15;
    int rest = idx >> 4;
    int d  = rest % D_INNER;
    int bbr = rest / D_INNER;      // 0..3
    int bb = bbr & 1, br = bbr >> 1;

    const float* Alog = br ? AlB : AlF;
    float An = -__expf(Alog[d * N_STATE + n]);

    float h0 = 0.f;
    #pragma unroll
    for (int g = 0; g < G; ++g) {
        size_t base = (((size_t)(br*Bv + bb) * G + g) * D_INNER + d) * 16 + n;
        h0buf[base] = h0;
        float Se = Send[((size_t)(br*Bv + bb) * G + g) * D_INNER + d];
        h0 = __expf(An * Se) * h0 + h_end[base];
    }
}

// Pass 3: full per-chunk scan with initial h0 + gate + reversal -> bf16 ycat.
__global__ __launch_bounds__(128, 4)
void scan3(const float* __restrict__ xF, const float* __restrict__ dtF,
           const float* __restrict__ xdF, const float* __restrict__ xzF,
           const float* __restrict__ AlF, const float* __restrict__ DFp,
           const float* __restrict__ xB, const float* __restrict__ dtB,
           const float* __restrict__ xdB, const float* __restrict__ xzB,
           const float* __restrict__ AlB, const float* __restrict__ DBp,
           const float* __restrict__ h0buf, unsigned short* __restrict__ ycat)
{
    const int br = blockIdx.z;
    const int bb = blockIdx.y >> 3, g = blockIdx.y & 7;
    const int d0 = blockIdx.x * 8;

    const float* x    = br ? xB  : xF;
    const float* dt   = br ? dtB : dtF;
    const float* xd   = br ? xdB : xdF;
    const float* xz   = br ? xzB : xzF;
    const float* Alog = br ? AlB : AlF;
    const float* Dp   = br ? DBp : DFp;

    __shared__ float xs [2][8][PADL];
    __shared__ float dls[2][8][PADL];
    __shared__ float zs [2][8][PADL];
    __shared__ float Bss[2][16][PADL];
    __shared__ float Css[2][16][PADL];

    const int t = threadIdx.x;
    const int n = t & 15, dloc = t >> 4;

    const float* xg  = x  + ((size_t)bb * Lv + g * CH) * D_INNER + d0;
    const float* dtg = dt + ((size_t)bb * Lv + g * CH) * D_INNER + d0;
    const float* zg  = xz + ((size_t)bb * Lv + g * CH) * (2*D_INNER) + D_INNER + d0;
    const float* bcg = xd + ((size_t)bb * Lv + g * CH) * 128;

    const int sl = t >> 1, sdq = (t & 1) * 4;
    const int bl0 = t >> 2,         bq0 = (t & 3) * 4;
    const int bl1 = (t + 128) >> 2, bq1 = ((t + 128) & 3) * 4;

    f32x4 rx, rdt, rz, rb0, rb1, rc0, rc1;

    #define LOADG3(c) do {                                                       \
        int l0_ = (c) * 64;                                                      \
        rx  = *(const f32x4*)(xg  + (size_t)(l0_ + sl) * D_INNER + sdq);         \
        rdt = *(const f32x4*)(dtg + (size_t)(l0_ + sl) * D_INNER + sdq);         \
        rz  = *(const f32x4*)(zg  + (size_t)(l0_ + sl) * (2*D_INNER) + sdq);     \
        rb0 = *(const f32x4*)(bcg + (size_t)(l0_ + bl0) * 128 + DT_RANK           + bq0); \
        rb1 = *(const f32x4*)(bcg + (size_t)(l0_ + bl1) * 128 + DT_RANK           + bq1); \
        rc0 = *(const f32x4*)(bcg + (size_t)(l0_ + bl0) * 128 + DT_RANK + N_STATE + bq0); \
        rc1 = *(const f32x4*)(bcg + (size_t)(l0_ + bl1) * 128 + DT_RANK + N_STATE + bq1); \
    } while (0)

    #define WRITEL3(p) do {                                                     \
        _Pragma("unroll")                                                       \
        for (int j = 0; j < 4; j++) {                                           \
            xs [p][sdq+j][sl] = rx[j];                                          \
            dls[p][sdq+j][sl] = rdt[j];                                         \
            zs [p][sdq+j][sl] = rz[j];                                          \
            Bss[p][bq0+j][bl0] = rb0[j];                                        \
            Bss[p][bq1+j][bl1] = rb1[j];                                        \
            Css[p][bq0+j][bl0] = rc0[j];                                        \
            Css[p][bq1+j][bl1] = rc1[j];                                        \
        }                                                                       \
    } while (0)

    const float An = -__expf(Alog[(d0 + dloc) * N_STATE + n]);
    const float Dd = Dp[d0 + dloc];
    float h = h0buf[(((size_t)(br*Bv + bb) * G + g) * D_INNER + d0 + dloc) * 16 + n];

    LOADG3(0);
    WRITEL3(0);
    __syncthreads();

    for (int c = 0; c < 2; ++c) {
        const int p = c;
        if (c == 0) LOADG3(1);

        float yq[4] = {};
        #pragma unroll
        for (int gg = 0; gg < 16; ++gg) {
            f32x4 xv  = *(const f32x4*)&xs [p][dloc][gg*4];
            f32x4 dtv = *(const f32x4*)&dls[p][dloc][gg*4];
            f32x4 zv  = *(const f32x4*)&zs [p][dloc][gg*4];
            f32x4 bv  = *(const f32x4*)&Bss[p][n][gg*4];
            f32x4 cv  = *(const f32x4*)&Css[p][n][gg*4];
            #pragma unroll
            for (int j = 0; j < 4; ++j) {
                const int l = gg * 4 + j;
                float ab = __expf(dtv[j] * An);
                h = fmaf(ab, h, dtv[j] * xv[j] * bv[j]);
                float contrib = h * cv[j];
                contrib = dpp_ror_add<0x121>(contrib);
                contrib = dpp_ror_add<0x122>(contrib);
                contrib = dpp_ror_add<0x124>(contrib);
                contrib = dpp_ror_add<0x128>(contrib);
                float y = (contrib + xv[j] * Dd)
                        * (zv[j] * __builtin_amdgcn_rcpf(1.f + __expf(-zv[j])));
                if ((l & 15) == n) yq[l >> 4] = y;
            }
        }
        if (c == 0) { WRITEL3(1); }

        #pragma unroll
        for (int q = 0; q < 4; ++q) {
            int gl = g * CH + c * 64 + q * 16 + n;
            int lo = br ? (Lv - 1 - gl) : gl;
            ycat[((size_t)bb * Lv + lo) * (2*D_INNER) + br * D_INNER + d0 + dloc] = f2bf(yq[q]);
        }
        __syncthreads();
    }
    #undef LOADG3
    #undef WRITEL3
}

extern "C" void kernel_launch(void* const* d_in, const int* in_sizes, int n_in,
                              void* d_out, int out_size, void* d_ws, size_t ws_size,
                              hipStream_t stream)
{
    (void)in_sizes; (void)n_in; (void)out_size; (void)ws_size;
    const float* u        = (const float*)d_in[0];
    const float* norm_w   = (const float*)d_in[1];
    const float* norm_b   = (const float*)d_in[2];
    const float* f_in_w   = (const float*)d_in[3];
    const float* f_conv_w = (const float*)d_in[4];
    const float* f_conv_b = (const float*)d_in[5];
    const float* f_Alog   = (const float*)d_in[6];
    const float* f_xproj  = (const float*)d_in[7];
    const float* f_dt_w   = (const float*)d_in[8];
    const float* f_dt_b   = (const float*)d_in[9];
    const float* f_D      = (const float*)d_in[10];
    const float* b_in_w   = (const float*)d_in[11];
    const float* b_conv_w = (const float*)d_in[12];
    const float* b_conv_b = (const float*)d_in[13];
    const float* b_Alog   = (const float*)d_in[14];
    const float* b_xproj  = (const float*)d_in[15];
    const float* b_dt_w   = (const float*)d_in[16];
    const float* b_dt_b   = (const float*)d_in[17];
    const float* b_D      = (const float*)d_in[18];
    const float* out_w    = (const float*)d_in[19];
    float* out = (float*)d_out;

    float* p = (float*)d_ws;
    unsigned short* un_bf = (unsigned short*)p;  p += (size_t)MROWS * D_MODEL;
    float* xz_f   = p;  p += (size_t)MROWS * 2 * D_INNER;
    float* xz_b   = p;  p += (size_t)MROWS * 2 * D_INNER;
    float* x_f    = p;  p += (size_t)MROWS * D_INNER;
    float* x_b    = p;  p += (size_t)MROWS * D_INNER;
    unsigned short* xbf_f = (unsigned short*)p;  p += (size_t)MROWS * D_INNER / 2;
    unsigned short* xbf_b = (unsigned short*)p;  p += (size_t)MROWS * D_INNER / 2;
    float* xdbl_f = p;  p += (size_t)MROWS * 128;
    float* xdbl_b = p;  p += (size_t)MROWS * 128;
    float* dt_f   = p;  p += (size_t)MROWS * D_INNER;
    float* dt_b_  = p;  p += (size_t)MROWS * D_INNER;
    unsigned short* yc_bf = (unsigned short*)p;  p += (size_t)MROWS * D_INNER;
    unsigned short* fw_bf = (unsigned short*)p;  p += (size_t)D_INNER * D_MODEL;
    unsigned short* bw_bf = (unsigned short*)p;  p += (size_t)D_INNER * D_MODEL;
    unsigned short* xwf_bf = (unsigned short*)p; p += (size_t)64 * D_INNER;
    unsigned short* xwb_bf = (unsigned short*)p; p += (size_t)64 * D_INNER;
    unsigned short* ow_bf = (unsigned short*)p;  p += (size_t)D_MODEL * D_INNER;
    float* h_end  = p;  p += (size_t)2 * Bv * G * D_INNER * N_STATE;      // 3.1 MB
    float* h0buf  = p;  p += (size_t)2 * Bv * G * D_INNER * N_STATE;      // 3.1 MB
    float* Send   = p;  p += (size_t)2 * Bv * G * D_INNER;                // 0.2 MB
    unsigned short* xdbf_f = (unsigned short*)p; p += (size_t)MROWS * 128 / 2;
    unsigned short* xdbf_b = (unsigned short*)p; p += (size_t)MROWS * 128 / 2;
    unsigned short* dtwf_bf = (unsigned short*)p; p += (size_t)D_INNER * DT_RANK / 2;
    unsigned short* dtwb_bf = (unsigned short*)p; p += (size_t)D_INNER * DT_RANK / 2;

    // 1. LayerNorm -> bf16
    ln_kernel<<<MROWS, 256, 0, stream>>>(u, norm_w, norm_b, un_bf);

    // 2. weight conversions to bf16
    f2b<<<(2*D_INNER*D_MODEL/4 + 255)/256, 256, 0, stream>>>(f_in_w, fw_bf, 2*D_INNER*D_MODEL/4);
    f2b<<<(2*D_INNER*D_MODEL/4 + 255)/256, 256, 0, stream>>>(b_in_w, bw_bf, 2*D_INNER*D_MODEL/4);
    f2b<<<(128*D_INNER/4 + 255)/256, 256, 0, stream>>>(f_xproj, xwf_bf, 128*D_INNER/4);
    f2b<<<(128*D_INNER/4 + 255)/256, 256, 0, stream>>>(b_xproj, xwb_bf, 128*D_INNER/4);
    f2b<<<(D_MODEL*2*D_INNER/4 + 255)/256, 256, 0, stream>>>(out_w, ow_bf, D_MODEL*2*D_INNER/4);
    f2b<<<(D_INNER*DT_RANK/4 + 255)/256, 256, 0, stream>>>(f_dt_w, dtwf_bf, D_INNER*DT_RANK/4);
    f2b<<<(D_INNER*DT_RANK/4 + 255)/256, 256, 0, stream>>>(b_dt_w, dtwb_bf, D_INNER*DT_RANK/4);

    // 3. in-proj GEMMs (bf16 MFMA; bwd reads reversed rows)
    gemm_mfma<<<dim3(2*D_INNER/128, MROWS/128), 256, 0, stream>>>(
        un_bf, D_MODEL, 0, Lv, fw_bf, nullptr, 0, nullptr, xz_f, MROWS, 2*D_INNER, D_MODEL);
    gemm_mfma<<<dim3(2*D_INNER/128, MROWS/128), 256, 0, stream>>>(
        un_bf, D_MODEL, 1, Lv, bw_bf, nullptr, 0, nullptr, xz_b, MROWS, 2*D_INNER, D_MODEL);

    // 4. conv + SiLU (dual fp32 + bf16 outputs)
    int convBlocks = (Bv * (Lv/8) * D_INNER) / 256;
    conv_silu<<<convBlocks, 256, 0, stream>>>(xz_f, f_conv_w, f_conv_b, x_f, xbf_f);
    conv_silu<<<convBlocks, 256, 0, stream>>>(xz_b, b_conv_w, b_conv_b, x_b, xbf_b);

    // 5. x-proj GEMMs (bf16 MFMA, N=128)
    gemm_mfma<<<dim3(1, MROWS/128), 256, 0, stream>>>(
        xbf_f, D_INNER, 0, Lv, xwf_bf, nullptr, 0, nullptr, xdbl_f, MROWS, 128, D_INNER);
    gemm_mfma<<<dim3(1, MROWS/128), 256, 0, stream>>>(
        xbf_b, D_INNER, 0, Lv, xwb_bf, nullptr, 0, nullptr, xdbl_b, MROWS, 128, D_INNER);

    // 6. xdbl -> bf16, then dt GEMMs (bf16 MFMA + bias + softplus)
    f2b<<<(MROWS*128/4 + 255)/256, 256, 0, stream>>>(xdbl_f, xdbf_f, MROWS*128/4);
    f2b<<<(MROWS*128/4 + 255)/256, 256, 0, stream>>>(xdbl_b, xdbf_b, MROWS*128/4);
    gemm_mfma<<<dim3(D_INNER/128, MROWS/128), 256, 0, stream>>>(
        xdbf_f, 128, 0, Lv, dtwf_bf, f_dt_b, 2, nullptr, dt_f, MROWS, D_INNER, DT_RANK);
    gemm_mfma<<<dim3(D_INNER/128, MROWS/128), 256, 0, stream>>>(
        xdbf_b, 128, 0, Lv, dtwb_bf, b_dt_b, 2, nullptr, dt_b_, MROWS, D_INNER, DT_RANK);

    // 7. chunked selective scan (recompute structure)
    scan1<<<dim3(D_INNER/8, Bv*G, 2), 128, 0, stream>>>(
        x_f, dt_f, xdbl_f, f_Alog,
        x_b, dt_b_, xdbl_b, b_Alog, h_end, Send);
    scan2<<<(2*Bv*D_INNER*N_STATE)/256, 256, 0, stream>>>(
        Send, f_Alog, b_Alog, h_end, h0buf);
    scan3<<<dim3(D_INNER/8, Bv*G, 2), 128, 0, stream>>>(
        x_f, dt_f, xdbl_f, xz_f, f_Alog, f_D,
        x_b, dt_b_, xdbl_b, xz_b, b_Alog, b_D, h0buf, yc_bf);

    // 8. out-proj GEMM (bf16 MFMA) + residual
    gemm_mfma<<<dim3(D_MODEL/128, MROWS/128), 256, 0, stream>>>(
        yc_bf, 2*D_INNER, 0, Lv, ow_bf, nullptr, 0, u, out, MROWS, D_MODEL, 2*D_INNER);
}